// Round 3
// baseline (34.185 us; speedup 1.0000x reference)
//
#include <hip/hip_runtime.h>

__device__ __forceinline__ void process_row(float4* lds, int s,
                                            float M0, float M1, float M2,
                                            float invM0, float invM1, float invM2)
{
    float4 v0 = lds[s + 0];
    float4 v1 = lds[s + 1];
    float4 v2 = lds[s + 2];

    // Row layout: x1 y1 x2 y2 | x3 y3 p1x p1y | p2x p2y p3x p3y
    float x1 = v0.x, y1 = v0.y, x2 = v0.z, y2 = v0.w;
    float x3 = v1.x, y3 = v1.y;
    float p1x = v1.z, p1y = v1.w;
    float p2x = v2.x, p2y = v2.y, p3x = v2.z, p3y = v2.w;

    float dx12 = x1 - x2, dy12 = y1 - y2;
    float dx13 = x1 - x3, dy13 = y1 - y3;
    float dx23 = x2 - x3, dy23 = y2 - y3;

    float s12 = dx12 * dx12 + dy12 * dy12;
    float s13 = dx13 * dx13 + dy13 * dy13;
    float s23 = dx23 * dx23 + dy23 * dy23;

    // 1/r^3 = rsq(s)^3  (G = 1)
    float i12 = __builtin_amdgcn_rsqf(s12);
    float i13 = __builtin_amdgcn_rsqf(s13);
    float i23 = __builtin_amdgcn_rsqf(s23);
    float a = (M0 * M1) * (i12 * i12 * i12);
    float b = (M0 * M2) * (i13 * i13 * i13);
    float c = (M1 * M2) * (i23 * i23 * i23);

    float4 o0, o1, o2;
    o0.x = p1x * invM0;
    o0.y = p1y * invM0;
    o0.z = p2x * invM1;
    o0.w = p2y * invM1;
    o1.x = p3x * invM2;
    o1.y = p3y * invM2;
    o1.z = -(a + b) * x1 + a * x2 + b * x3;
    o1.w = -(a + b) * y1 + a * y2 + b * y3;
    o2.x = a * x1 - (a + c) * x2 + c * x3;
    o2.y = a * y1 - (a + c) * y2 + c * y3;
    o2.z = b * x1 + c * x2 - (b + c) * x3;
    o2.w = b * y1 + c * y2 - (b + c) * y3;

    // In-place overwrite: this slot is private to the owning thread
    // between the two block barriers.
    lds[s + 0] = o0;
    lds[s + 1] = o1;
    lds[s + 2] = o2;
}

__global__ __launch_bounds__(256) void ham3body_kernel(
    const float4* __restrict__ y4,
    const float* __restrict__ M,
    float4* __restrict__ o4,
    int B)
{
    __shared__ float4 lds[1536];   // 512 rows x 3 float4 = 24 KB

    const int t = threadIdx.x;
    const long nf4 = (long)B * 3;
    const long base = (long)blockIdx.x * 1536;

    // ---- stage in: 6 fully-coalesced, independent float4 loads ----
#pragma unroll
    for (int k = 0; k < 6; ++k) {
        long idx = base + k * 256 + t;
        if (idx < nf4) lds[k * 256 + t] = y4[idx];
    }

    const float M0 = M[0], M1 = M[1], M2 = M[2];
    const float invM0 = 1.0f / M0, invM1 = 1.0f / M1, invM2 = 1.0f / M2;

    __syncthreads();

    // Thread t owns rows t and t+256 of this block's 512-row tile.
    // Slot pattern 3t: 2-way bank aliasing only (free, m136).
    process_row(lds, 3 * t,       M0, M1, M2, invM0, invM1, invM2);
    process_row(lds, 768 + 3 * t, M0, M1, M2, invM0, invM1, invM2);

    __syncthreads();

    // ---- stage out: 6 fully-coalesced float4 stores ----
#pragma unroll
    for (int k = 0; k < 6; ++k) {
        long idx = base + k * 256 + t;
        if (idx < nf4) o4[idx] = lds[k * 256 + t];
    }
}

extern "C" void kernel_launch(void* const* d_in, const int* in_sizes, int n_in,
                              void* d_out, int out_size, void* d_ws, size_t ws_size,
                              hipStream_t stream) {
    const float4* y = (const float4*)d_in[0];
    const float* M = (const float*)d_in[1];
    float4* out = (float4*)d_out;

    int B = in_sizes[0] / 12;
    int rowsPerBlock = 512;
    int grid = (B + rowsPerBlock - 1) / rowsPerBlock;
    ham3body_kernel<<<grid, 256, 0, stream>>>(y, M, out, B);
}

// Round 5
// 32.873 us; speedup vs baseline: 1.0399x; 1.0399x over previous
//
#include <hip/hip_runtime.h>

typedef float f32x4 __attribute__((ext_vector_type(4)));

__global__ __launch_bounds__(256) void ham3body_kernel(
    const float4* __restrict__ y4,
    const float* __restrict__ M,
    float4* __restrict__ o4,
    int B)
{
    __shared__ float4 lds[768];   // 256 rows x 3 float4 = 12 KB

    const int t = threadIdx.x;
    const int wave = t >> 6;
    const long nf4 = (long)B * 3;
    const long base = (long)blockIdx.x * 768;

    // ---- stage in: async global->LDS, width 16, linear layout ----
    // LDS dest is wave-uniform base + lane*16 (HW rule); our layout is
    // exactly linear so lane l lands at lds[k*256 + wave*64 + l].
#pragma unroll
    for (int k = 0; k < 3; ++k) {
        long idx = base + k * 256 + t;
        if (idx < nf4) {
            __builtin_amdgcn_global_load_lds(
                (const __attribute__((address_space(1))) void*)(y4 + idx),
                (__attribute__((address_space(3))) void*)&lds[k * 256 + wave * 64],
                16, 0, 0);
        }
    }

    const float M0 = M[0], M1 = M[1], M2 = M[2];
    const float invM0 = 1.0f / M0, invM1 = 1.0f / M1, invM2 = 1.0f / M2;

    __syncthreads();   // drains vmcnt for the async LDS loads

    // ---- compute: thread t owns LDS slots [3t, 3t+2]; reads then
    // overwrites its OWN slots -> no barrier needed in between ----
    const int s = 3 * t;
    float4 v0 = lds[s + 0];
    float4 v1 = lds[s + 1];
    float4 v2 = lds[s + 2];

    // Row layout: x1 y1 x2 y2 | x3 y3 p1x p1y | p2x p2y p3x p3y
    float x1 = v0.x, y1 = v0.y, x2 = v0.z, y2 = v0.w;
    float x3 = v1.x, y3 = v1.y;
    float p1x = v1.z, p1y = v1.w;
    float p2x = v2.x, p2y = v2.y, p3x = v2.z, p3y = v2.w;

    float dx12 = x1 - x2, dy12 = y1 - y2;
    float dx13 = x1 - x3, dy13 = y1 - y3;
    float dx23 = x2 - x3, dy23 = y2 - y3;

    float s12 = dx12 * dx12 + dy12 * dy12;
    float s13 = dx13 * dx13 + dy13 * dy13;
    float s23 = dx23 * dx23 + dy23 * dy23;

    // 1/r^3 = rsq(s)^3  (G = 1)
    float i12 = __builtin_amdgcn_rsqf(s12);
    float i13 = __builtin_amdgcn_rsqf(s13);
    float i23 = __builtin_amdgcn_rsqf(s23);
    float a = (M0 * M1) * (i12 * i12 * i12);
    float b = (M0 * M2) * (i13 * i13 * i13);
    float c = (M1 * M2) * (i23 * i23 * i23);

    float4 o0, o1, o2;
    o0.x = p1x * invM0;
    o0.y = p1y * invM0;
    o0.z = p2x * invM1;
    o0.w = p2y * invM1;
    o1.x = p3x * invM2;
    o1.y = p3y * invM2;
    o1.z = -(a + b) * x1 + a * x2 + b * x3;
    o1.w = -(a + b) * y1 + a * y2 + b * y3;
    o2.x = a * x1 - (a + c) * x2 + c * x3;
    o2.y = a * y1 - (a + c) * y2 + c * y3;
    o2.z = b * x1 + c * x2 - (b + c) * x3;
    o2.w = b * y1 + c * y2 - (b + c) * y3;

    lds[s + 0] = o0;
    lds[s + 1] = o1;
    lds[s + 2] = o2;

    __syncthreads();

    // ---- stage out: coalesced NON-TEMPORAL stores (evict-first in L2/L3
    // so the output stream doesn't displace the L3-resident input) ----
    const f32x4* ldsv = reinterpret_cast<const f32x4*>(lds);
    f32x4* outv = reinterpret_cast<f32x4*>(o4);
#pragma unroll
    for (int k = 0; k < 3; ++k) {
        long idx = base + k * 256 + t;
        if (idx < nf4) {
            __builtin_nontemporal_store(ldsv[k * 256 + t], &outv[idx]);
        }
    }
}

extern "C" void kernel_launch(void* const* d_in, const int* in_sizes, int n_in,
                              void* d_out, int out_size, void* d_ws, size_t ws_size,
                              hipStream_t stream) {
    const float4* y = (const float4*)d_in[0];
    const float* M = (const float*)d_in[1];
    float4* out = (float4*)d_out;

    int B = in_sizes[0] / 12;
    int rowsPerBlock = 256;
    int grid = (B + rowsPerBlock - 1) / rowsPerBlock;
    ham3body_kernel<<<grid, 256, 0, stream>>>(y, M, out, B);
}